// Round 4
// baseline (1593.447 us; speedup 1.0000x reference)
//
#include <hip/hip_runtime.h>
#include <stdint.h>

#define T_TOK 4096
#define HDIM  1024
#define DDIM  4096
#define NEXP  8
#define NSLOT (2 * T_TOK)   // top_k=2 -> 8192 slots total, always

typedef unsigned short ushort_t;
typedef __attribute__((ext_vector_type(8))) short bf16x8;   // 8 bf16 = 4 VGPRs
typedef __attribute__((ext_vector_type(4))) float f32x4;

__device__ __forceinline__ float bf2f(ushort_t b) {
  return __uint_as_float(((unsigned int)b) << 16);
}
__device__ __forceinline__ unsigned int f2bf(float f) {  // round-to-nearest-even
  unsigned int u = __float_as_uint(f);
  return (u + 0x7fffu + ((u >> 16) & 1u)) >> 16;
}

// ---------------- routing (fp32 in, fp32 sparse_w out) ----------------
__global__ void k_init(int* counts) {
  if (threadIdx.x < NEXP) counts[threadIdx.x] = 0;
}

__global__ void k_route(const float* __restrict__ rw, float* __restrict__ sw_out,
                        int* counts, int* inv_e, int* inv_p, float* inv_w,
                        int* tokA) {
  int t = blockIdx.x * 256 + threadIdx.x;
  if (t >= T_TOK) return;
  float v[NEXP];
#pragma unroll
  for (int e = 0; e < NEXP; e++) v[e] = rw[t * NEXP + e];
  int i0 = 0; float m0 = v[0];
#pragma unroll
  for (int e = 1; e < NEXP; e++) if (v[e] > m0) { m0 = v[e]; i0 = e; }
  int i1 = -1; float m1 = -1e30f;
#pragma unroll
  for (int e = 0; e < NEXP; e++) if (e != i0 && v[e] > m1) { m1 = v[e]; i1 = e; }
  float s = m0 + m1 + 1e-8f;
  float w0 = m0 / s, w1 = m1 / s;
#pragma unroll
  for (int e = 0; e < NEXP; e++) {
    float w = (e == i0) ? w0 : ((e == i1) ? w1 : 0.0f);
    sw_out[t * NEXP + e] = w;
  }
  int p0 = atomicAdd(&counts[i0], 1);
  int p1 = atomicAdd(&counts[i1], 1);
  tokA[i0 * T_TOK + p0] = t;
  tokA[i1 * T_TOK + p1] = t;
  inv_e[t * 2] = i0; inv_e[t * 2 + 1] = i1;
  inv_p[t * 2] = p0; inv_p[t * 2 + 1] = p1;
  inv_w[t * 2] = w0; inv_w[t * 2 + 1] = w1;
}

__global__ void k_offsets(const int* counts, int* offsets) {
  int acc = 0;
  for (int e = 0; e < NEXP; e++) { offsets[e] = acc; acc += counts[e]; }
}

__global__ void k_slotmap(const int* __restrict__ counts, const int* __restrict__ offsets,
                          const int* __restrict__ tokA, int* __restrict__ slotTok) {
  int e = blockIdx.x;
  int cnt = counts[e], off = offsets[e];
  for (int p = threadIdx.x; p < cnt; p += 256)
    slotTok[off + p] = tokA[e * T_TOK + p];
}

// gather X rows into slot order, fp32 -> bf16
__global__ void k_gatherx(const float* __restrict__ x, const int* __restrict__ slotTok,
                          ushort_t* __restrict__ Xg) {
  int gid = blockIdx.x * 256 + threadIdx.x;
  int slot = gid >> 7;            // 128 chunks of 8 elems per row (H=1024)
  int hc   = (gid & 127) * 8;
  int t = slotTok[slot];
  const float* src = x + (size_t)t * HDIM + hc;
  float4 f0 = *(const float4*)src;
  float4 f1 = *(const float4*)(src + 4);
  uint4 q;
  q.x = f2bf(f0.x) | (f2bf(f0.y) << 16);
  q.y = f2bf(f0.z) | (f2bf(f0.w) << 16);
  q.z = f2bf(f1.x) | (f2bf(f1.y) << 16);
  q.w = f2bf(f1.z) | (f2bf(f1.w) << 16);
  *(uint4*)(Xg + (size_t)slot * HDIM + hc) = q;
}

// W [E][K][N] fp32 -> WT [E][N][K] bf16, 64x64 LDS tiles
__global__ void k_cvt_transpose(const float* __restrict__ W, ushort_t* __restrict__ WT,
                                int K, int N) {
  __shared__ short t_sh[64][72];   // 72 stride: 144B rows, 16B-aligned b128 reads
  int e = blockIdx.z, n0 = blockIdx.x * 64, k0 = blockIdx.y * 64;
  int tid = threadIdx.x;
  const float* src = W + ((size_t)e * K + k0) * N + n0;
  int nf4 = tid & 15, kr = tid >> 4;
#pragma unroll
  for (int i = 0; i < 4; i++) {
    int k = i * 16 + kr;
    float4 v = *(const float4*)(src + (size_t)k * N + nf4 * 4);
    t_sh[nf4 * 4 + 0][k] = (short)f2bf(v.x);
    t_sh[nf4 * 4 + 1][k] = (short)f2bf(v.y);
    t_sh[nf4 * 4 + 2][k] = (short)f2bf(v.z);
    t_sh[nf4 * 4 + 3][k] = (short)f2bf(v.w);
  }
  __syncthreads();
  int kc = tid & 7, nr = tid >> 3;
  ushort_t* dst = WT + ((size_t)e * N + n0) * K + k0;
#pragma unroll
  for (int i = 0; i < 2; i++) {
    int n = i * 32 + nr;
    uint4 q = *(const uint4*)(&t_sh[n][kc * 8]);
    *(uint4*)(dst + (size_t)n * K + kc * 8) = q;
  }
}

// ---------------- grouped GEMM, all-bf16, 128x128 tile, BK=64, pipelined ----------------
// A: [slot][K] bf16 contiguous (Xg or Z). B: WT [E][N][K] bf16.
// LDS: [row][k], 8 chunks of 8 bf16/row; physical chunk p of row r = global chunk p^(r&7).
template <int KDIM, int NDIM, bool DOWN>
__global__ __launch_bounds__(256, 3)
void k_gemm(const ushort_t* __restrict__ Abase, const ushort_t* __restrict__ WT,
            const float* __restrict__ bias, const int* __restrict__ counts,
            const int* __restrict__ offsets, ushort_t* __restrict__ Out) {
  __shared__ short a_sh[128 * 64];
  __shared__ short b_sh[128 * 64];
  const int e    = blockIdx.y >> 5;
  const int tile = blockIdx.y & 31;
  const int cnt  = counts[e];
  if (tile * 128 >= cnt) return;
  const int off_e = offsets[e];
  const int zbase = off_e + tile * 128;
  const int n0    = blockIdx.x * 128;
  const int tid  = threadIdx.x;
  const int wave = tid >> 6;
  const int lane = tid & 63;
  const int rgrp = lane >> 3;      // row within 8-row group
  const int lc   = lane & 7;       // global 16B k-chunk
  const int pc   = lc ^ rgrp;      // swizzled physical chunk (row&7 == rgrp)

  const ushort_t* aptr[4];
  const ushort_t* bptr[4];
  int lds_o[4];
#pragma unroll
  for (int i = 0; i < 4; i++) {
    int rl = wave * 32 + i * 8 + rgrp;
    lds_o[i] = rl * 64 + pc * 8;
    int ridx = tile * 128 + rl;
    int ridx_c = (ridx < cnt) ? ridx : tile * 128;   // clamp to valid row
    aptr[i] = Abase + (size_t)(off_e + ridx_c) * KDIM + lc * 8;
    bptr[i] = WT + ((size_t)e * NDIM + n0 + rl) * KDIM + lc * 8;
  }

  const int lm   = lane & 15;
  const int quad = lane >> 4;

  f32x4 acc[8][2];
  const f32x4 zero = {0.0f, 0.0f, 0.0f, 0.0f};
#pragma unroll
  for (int mf = 0; mf < 8; mf++)
#pragma unroll
    for (int nf = 0; nf < 2; nf++) acc[mf][nf] = zero;

  uint4 aval[4], bval[4];
#pragma unroll
  for (int i = 0; i < 4; i++) {
    aval[i] = *(const uint4*)(aptr[i]);
    bval[i] = *(const uint4*)(bptr[i]);
  }

  for (int k0 = 0; k0 < KDIM; k0 += 64) {
#pragma unroll
    for (int i = 0; i < 4; i++) *(uint4*)(a_sh + lds_o[i]) = aval[i];
#pragma unroll
    for (int i = 0; i < 4; i++) *(uint4*)(b_sh + lds_o[i]) = bval[i];
    __syncthreads();
    if (k0 + 64 < KDIM) {        // prefetch next k-tile during compute
      int kn = k0 + 64;
#pragma unroll
      for (int i = 0; i < 4; i++) {
        aval[i] = *(const uint4*)(aptr[i] + kn);
        bval[i] = *(const uint4*)(bptr[i] + kn);
      }
    }
#pragma unroll
    for (int ks = 0; ks < 2; ks++) {
      const int cbase = ((ks * 4 + quad) ^ (lm & 7)) * 8;
      bf16x8 bfv[2];
#pragma unroll
      for (int nf = 0; nf < 2; nf++)
        bfv[nf] = *(const bf16x8*)(b_sh + (wave * 32 + nf * 16 + lm) * 64 + cbase);
#pragma unroll
      for (int mf = 0; mf < 8; mf++) {
        bf16x8 af = *(const bf16x8*)(a_sh + (mf * 16 + lm) * 64 + cbase);
#pragma unroll
        for (int nf = 0; nf < 2; nf++)
          acc[mf][nf] = __builtin_amdgcn_mfma_f32_16x16x32_bf16(af, bfv[nf], acc[mf][nf], 0, 0, 0);
      }
    }
    __syncthreads();
  }

  // epilogue: C/D layout col(n)=lane&15, row(m)=quad*4+reg
  float bv[2] = {0.0f, 0.0f};
  if constexpr (DOWN) {
#pragma unroll
    for (int nf = 0; nf < 2; nf++)
      bv[nf] = bias[e * NDIM + n0 + wave * 32 + nf * 16 + lm];
  }
#pragma unroll
  for (int mf = 0; mf < 8; mf++) {
#pragma unroll
    for (int nf = 0; nf < 2; nf++) {
      int ncol = n0 + wave * 32 + nf * 16 + lm;
#pragma unroll
      for (int r = 0; r < 4; r++) {
        int m = mf * 16 + quad * 4 + r;
        if (tile * 128 + m < cnt) {
          size_t row = (size_t)(zbase + m);
          float v = acc[mf][nf][r];
          if constexpr (DOWN) {
            float zv = v + bv[nf];
            v = 0.5f * zv * (1.0f + erff(zv * 0.70710678118654752f));  // exact GELU
          }
          Out[row * NDIM + ncol] = (ushort_t)f2bf(v);
        }
      }
    }
  }
}

// ---------------- combine: out[t] = w0*U[slot0] + w1*U[slot1] (fp32 out) ----------------
__global__ void k_combine(const ushort_t* __restrict__ U, const int* __restrict__ inv_e,
                          const int* __restrict__ inv_p, const float* __restrict__ inv_w,
                          const int* __restrict__ offsets, float* __restrict__ out) {
  int gid = blockIdx.x * 256 + threadIdx.x;
  int t  = gid >> 7;
  int hc = (gid & 127) * 8;
  int e0 = inv_e[t * 2], e1 = inv_e[t * 2 + 1];
  size_t s0 = (size_t)offsets[e0] + inv_p[t * 2];
  size_t s1 = (size_t)offsets[e1] + inv_p[t * 2 + 1];
  float w0 = inv_w[t * 2], w1 = inv_w[t * 2 + 1];
  uint4 q0 = *(const uint4*)(U + s0 * HDIM + hc);
  uint4 q1 = *(const uint4*)(U + s1 * HDIM + hc);
  const ushort_t* a = (const ushort_t*)&q0;
  const ushort_t* b = (const ushort_t*)&q1;
  float4 o0, o1;
  o0.x = w0 * bf2f(a[0]) + w1 * bf2f(b[0]);
  o0.y = w0 * bf2f(a[1]) + w1 * bf2f(b[1]);
  o0.z = w0 * bf2f(a[2]) + w1 * bf2f(b[2]);
  o0.w = w0 * bf2f(a[3]) + w1 * bf2f(b[3]);
  o1.x = w0 * bf2f(a[4]) + w1 * bf2f(b[4]);
  o1.y = w0 * bf2f(a[5]) + w1 * bf2f(b[5]);
  o1.z = w0 * bf2f(a[6]) + w1 * bf2f(b[6]);
  o1.w = w0 * bf2f(a[7]) + w1 * bf2f(b[7]);
  float* op = out + (size_t)t * HDIM + hc;
  *(float4*)(op)     = o0;
  *(float4*)(op + 4) = o1;
}

extern "C" void kernel_launch(void* const* d_in, const int* in_sizes, int n_in,
                              void* d_out, int out_size, void* d_ws, size_t ws_size,
                              hipStream_t stream) {
  const float* x  = (const float*)d_in[0];  // [T, H] f32
  const float* rw = (const float*)d_in[1];  // [T, E] f32
  const float* wd = (const float*)d_in[2];  // [E, H, D] f32
  const float* bd = (const float*)d_in[3];  // [E, D] f32
  const float* wu = (const float*)d_in[4];  // [E, D, H] f32
  float* out    = (float*)d_out;
  float* sw_out = out + (size_t)T_TOK * HDIM;

  char* ws = (char*)d_ws;
  int*   counts  = (int*)(ws);
  int*   offs    = (int*)(ws + 64);
  int*   inv_e   = (int*)(ws + 128);
  int*   inv_p   = (int*)(ws + 128 + 32768);
  float* inv_w   = (float*)(ws + 128 + 65536);
  int*   slotTok = (int*)(ws + 128 + 98304);
  int*   tokA    = (int*)(ws + 128 + 131072);                  // [E][T], 128 KB
  const size_t MB = 1024 * 1024;
  ushort_t* Xg  = (ushort_t*)(ws + (512 * 1024));              // 16 MB [8192][1024] bf16
  ushort_t* Z   = (ushort_t*)(ws + (512 * 1024) + 16 * MB);    // 64 MB [8192][4096] bf16
  ushort_t* WdT = (ushort_t*)(ws + (512 * 1024) + 80 * MB);    // 64 MB [E][D][H] bf16
  ushort_t* WuT = (ushort_t*)(ws + (512 * 1024) + 144 * MB);   // 64 MB [E][H][D] bf16
  ushort_t* U   = Xg;  // Xg dead after down-GEMM; reuse for U (16 MB)

  k_init<<<1, 64, 0, stream>>>(counts);
  k_route<<<T_TOK / 256, 256, 0, stream>>>(rw, sw_out, counts, inv_e, inv_p, inv_w, tokA);
  k_offsets<<<1, 1, 0, stream>>>(counts, offs);
  k_slotmap<<<NEXP, 256, 0, stream>>>(counts, offs, tokA, slotTok);
  k_gatherx<<<(NSLOT * (HDIM / 8)) / 256, 256, 0, stream>>>(x, slotTok, Xg);
  k_cvt_transpose<<<dim3(DDIM / 64, HDIM / 64, NEXP), 256, 0, stream>>>(wd, WdT, HDIM, DDIM);
  k_cvt_transpose<<<dim3(HDIM / 64, DDIM / 64, NEXP), 256, 0, stream>>>(wu, WuT, DDIM, HDIM);
  k_gemm<HDIM, DDIM, true><<<dim3(DDIM / 128, NEXP * 32), 256, 0, stream>>>(
      Xg, WdT, bd, counts, offs, Z);
  k_gemm<DDIM, HDIM, false><<<dim3(HDIM / 128, NEXP * 32), 256, 0, stream>>>(
      Z, WuT, nullptr, counts, offs, U);
  k_combine<<<(T_TOK * (HDIM / 8)) / 256, 256, 0, stream>>>(U, inv_e, inv_p, inv_w, offs, out);
}